// Round 18
// baseline (359.062 us; speedup 1.0000x reference)
//
#include <hip/hip_runtime.h>
#include <hip/hip_bf16.h>
#include <math.h>

// NoisyTopkRouter: rows=32768, D=4096, E=64, k=8.
// R18 = R17 race-fixed. 256-thr blocks, BM=16, 128 vcols, LDS 20KB ->
// 6 blocks/CU (decorrelated barrier domains). W single-buffer with
// OWNERSHIP mapping (wave w DMAs exactly the 2x2KB it alone reads ->
// per-wave vmcnt suffices); issue order pinned by sched_barrier so
// vmcnt(1) provably drains W DMAs each step. fp16x2 split, 3-term MFMA,
// fold-16-tiles. Output (fp32): gates[rows*64] | ix[rows*8] | full[rows*64]

typedef __attribute__((ext_vector_type(8))) _Float16 f16x8;
typedef __attribute__((ext_vector_type(4))) float f32x4;
typedef unsigned int u32;

#define D_DIM 4096
#define NT 128              // k-tiles of 32
#define WTILE 16384         // per-k-tile W image: 2 planes x 8KB
#define HOFF 16384          // h region base in LDS
#define SMEM_BYTES 20480    // W 16KB + h 2buf x 2plane x 1KB

__device__ __forceinline__ float softplus_f(float x) {
    return fmaxf(x, 0.0f) + log1pf(expf(-fabsf(x)));
}

__device__ __forceinline__ void gl16(void* lds, const void* g) {
    __builtin_amdgcn_global_load_lds(
        (const __attribute__((address_space(1))) u32*)g,
        (__attribute__((address_space(3))) u32*)lds, 16, 0, 0);
}

#define MFMA16F(A, B, C) __builtin_amdgcn_mfma_f32_16x16x32_f16((A), (B), (C), 0, 0, 0)

// ---- W pre-conversion (unchanged): 2 fp16 planes (p0=f16(w), p1=f16((w-p0)*2048)),
// per-k-tile 16KB image, chunk-swizzled sc = c4 ^ ((vrow>>2)&3)
__global__ __launch_bounds__(256)
void wconv_kernel(const float* __restrict__ Ww, const float* __restrict__ Wn,
                  char* __restrict__ Wp)
{
    const int bid = blockIdx.x;
    const int kc = bid >> 1, half = bid & 1;
    const int t = threadIdx.x;
    const int vrow = half * 64 + (t >> 2);
    const int c4 = t & 3;
    const float* src = (vrow < 64) ? (Ww + (size_t)vrow * D_DIM)
                                   : (Wn + (size_t)(vrow - 64) * D_DIM);
    const float4 a = *reinterpret_cast<const float4*>(src + kc * 32 + c4 * 8);
    const float4 b = *reinterpret_cast<const float4*>(src + kc * 32 + c4 * 8 + 4);
    const float f[8] = {a.x, a.y, a.z, a.w, b.x, b.y, b.z, b.w};
    union { _Float16 h[8]; uint4 q; } P0, P1;
#pragma unroll
    for (int i = 0; i < 8; ++i) {
        _Float16 lo = (_Float16)f[i];
        P0.h[i] = lo;
        P1.h[i] = (_Float16)((f[i] - (float)lo) * 2048.0f);
    }
    const int sc = c4 ^ ((vrow >> 2) & 3);
    char* dst = Wp + (size_t)kc * WTILE + vrow * 64 + sc * 16;
    *reinterpret_cast<uint4*>(dst)        = P0.q;
    *reinterpret_cast<uint4*>(dst + 8192) = P1.q;
}

__global__ __launch_bounds__(256, 6)
void router_kernel(const float* __restrict__ h,
                   const float* __restrict__ bw,
                   const float* __restrict__ bn,
                   const float* __restrict__ noise,
                   const char* __restrict__ Wp,
                   float* __restrict__ out_gates,
                   float* __restrict__ out_ix,
                   float* __restrict__ out_full)
{
    __shared__ __align__(16) char smem[SMEM_BYTES];

    const int t = threadIdx.x;
    const int lane = t & 63, w = t >> 6;     // 4 waves; wave w -> vcols w*32..+31
    const int c = lane & 15, kg = lane >> 4;
    // XCD-aware bijective swizzle (2048 % 8 == 0)
    const int bid = (int)blockIdx.x;
    const int row0 = ((bid & 7) * 256 + (bid >> 3)) * 16;   // 2048 blocks x 16 rows

    // ---- h staging: thread -> row t>>4 (0..15), 4B-granule t&15 (2 fp32/tile)
    const int hr = t >> 4, hg = t & 15;
    const float* hp = h + (size_t)(row0 + hr) * D_DIM + hg * 2;
    const int hgswz = (hg ^ (((hr >> 1) & 3) << 2)) * 4;    // swizzled byte col
    // ---- W staging, OWNERSHIP mapping: wave w copies bytes [w*2048, +2048)
    // of each plane = exactly its own B-read set. 4 gl16/thread/tile.
    const char* wsv = Wp + w * 2048 + lane * 16;   // + tile*16384 + p*8192 + q*1024

    // A-frag (h) read offsets: row c, 16B block kg swizzled by ((c>>1)&3)
    const int aswz = (kg ^ ((c >> 1) & 3)) * 16;
    // B-frag (W) offsets
    const int v0 = w * 32 + c;
    const int v1 = v0 + 16;
    const int bo0 = v0 * 64 + ((kg ^ ((v0 >> 2) & 3)) * 16);
    const int bo1 = v1 * 64 + ((kg ^ ((v1 >> 2) & 3)) * 16);

    f32x4 grp0 = (f32x4)0.0f, grp1 = (f32x4)0.0f;
    f32x4 sA0  = (f32x4)0.0f, sA1  = (f32x4)0.0f;
    f32x4 aM0  = (f32x4)0.0f, aM1  = (f32x4)0.0f;

    float2 hvA, hvB;

#define HCONV(BUF, V) {                                                       \
        union { _Float16 q[2]; u32 u; } Lo_, Hi_;                             \
        _Float16 x_;                                                          \
        x_ = (_Float16)(V).x; Lo_.q[0] = x_;                                  \
        Hi_.q[0] = (_Float16)(((V).x - (float)x_) * 2048.0f);                 \
        x_ = (_Float16)(V).y; Lo_.q[1] = x_;                                  \
        Hi_.q[1] = (_Float16)(((V).y - (float)x_) * 2048.0f);                 \
        *reinterpret_cast<u32*>(smem + HOFF + (BUF) * 2048 + hr * 64 + hgswz) = Lo_.u; \
        *reinterpret_cast<u32*>(smem + HOFF + (BUF) * 2048 + 1024 + hr * 64 + hgswz) = Hi_.u; \
    }

#define WDMA(TILE)                                                            \
    {                                                                         \
        const char* ws_ = wsv + (size_t)(TILE) * WTILE;                       \
        gl16(smem +        w * 2048,        ws_);                             \
        gl16(smem +        w * 2048 + 1024, ws_ + 1024);                      \
        gl16(smem + 8192 + w * 2048,        ws_ + 8192);                      \
        gl16(smem + 8192 + w * 2048 + 1024, ws_ + 9216);                      \
    }

    // ---- prologue: h(0), [pin] W(0)x4, [pin] h(1) ----
    hvA = *reinterpret_cast<const float2*>(hp);
    __builtin_amdgcn_sched_barrier(0);
    WDMA(0)
    __builtin_amdgcn_sched_barrier(0);
    hvB = *reinterpret_cast<const float2*>(hp + 32);
    asm volatile("s_waitcnt vmcnt(5)" ::: "memory");   // h(0) retired
    __builtin_amdgcn_sched_barrier(0);
    HCONV(0, hvA)
    asm volatile("s_waitcnt vmcnt(1) lgkmcnt(0)" ::: "memory");  // W(0) landed
    __builtin_amdgcn_sched_barrier(0);
    __builtin_amdgcn_s_barrier();
    __builtin_amdgcn_sched_barrier(0);

    // ---- main loop ----
#define STEP(S, ISS, CONV)                                                    \
    {                                                                         \
        const int s_ = (S);                                                   \
        const char* hb_ = smem + HOFF + (s_ & 1) * 2048;                      \
        const f16x8 A0_ = *reinterpret_cast<const f16x8*>(hb_ + c * 64 + aswz);        \
        const f16x8 A1_ = *reinterpret_cast<const f16x8*>(hb_ + 1024 + c * 64 + aswz); \
        const f16x8 B00_ = *reinterpret_cast<const f16x8*>(smem + bo0);       \
        const f16x8 B01_ = *reinterpret_cast<const f16x8*>(smem + 8192 + bo0);\
        const f16x8 B10_ = *reinterpret_cast<const f16x8*>(smem + bo1);       \
        const f16x8 B11_ = *reinterpret_cast<const f16x8*>(smem + 8192 + bo1);\
        asm volatile("s_waitcnt lgkmcnt(0)" ::: "memory");                    \
        __builtin_amdgcn_sched_barrier(0);                                    \
        if (s_ + 1 < NT) WDMA(s_ + 1)   /* own slice only: no x-wave hazard */\
        __builtin_amdgcn_sched_barrier(0);                                    \
        if (s_ + 2 < NT)                                                      \
            ISS = *reinterpret_cast<const float2*>(hp + (s_ + 2) * 32);       \
        __builtin_amdgcn_s_setprio(1);                                        \
        grp0 = MFMA16F(A0_, B00_, grp0);                                      \
        aM0  = MFMA16F(A0_, B01_, aM0);                                       \
        aM0  = MFMA16F(A1_, B00_, aM0);                                       \
        grp1 = MFMA16F(A0_, B10_, grp1);                                      \
        aM1  = MFMA16F(A0_, B11_, aM1);                                       \
        aM1  = MFMA16F(A1_, B10_, aM1);                                       \
        __builtin_amdgcn_s_setprio(0);                                        \
        if (s_ < 126)       asm volatile("s_waitcnt vmcnt(5)" ::: "memory");  \
        else if (s_ == 126) asm volatile("s_waitcnt vmcnt(4)" ::: "memory");  \
        else                asm volatile("s_waitcnt vmcnt(0)" ::: "memory");  \
        __builtin_amdgcn_sched_barrier(0);                                    \
        if (s_ + 1 < NT) HCONV(((s_ + 1) & 1), CONV)                          \
        if (s_ < 126)       asm volatile("s_waitcnt vmcnt(1) lgkmcnt(0)" ::: "memory"); \
        else                asm volatile("s_waitcnt vmcnt(0) lgkmcnt(0)" ::: "memory"); \
        __builtin_amdgcn_sched_barrier(0);                                    \
        __builtin_amdgcn_s_barrier();                                         \
        __builtin_amdgcn_sched_barrier(0);                                    \
    }

    for (int s = 0; s < NT; s += 2) {
        STEP(s,     hvA, hvB)
        STEP(s + 1, hvB, hvA)
        if (((s + 1) & 15) == 15) {   // fold every 16 k-tiles
#pragma unroll
            for (int e = 0; e < 4; ++e) {
                sA0[e] += grp0[e]; sA1[e] += grp1[e];
            }
            grp0 = (f32x4)0.0f; grp1 = (f32x4)0.0f;
        }
    }
#undef STEP

    // ---- logits -> LDS overlay (W region free now) ----
    __syncthreads();
    float* lw_s = reinterpret_cast<float*>(smem);     // [16][65]
    float* ln_s = lw_s + 16 * 65;                     // [16][65]
    {
        // D layout: col = c (h-row idx? no: col=N=c of B? see below)
        // A=h(row c), B=W(col v): D row = kg*4+e (h-row), col = c (vcol idx)
        float* dst = (w < 2) ? lw_s : ln_s;
        const int eb = (w & 1) * 32;
#pragma unroll
        for (int e = 0; e < 4; ++e) {
            dst[(kg * 4 + e) * 65 + eb +      c] = sA0[e] + aM0[e] * 4.8828125e-4f;
            dst[(kg * 4 + e) * 65 + eb + 16 + c] = sA1[e] + aM1[e] * 4.8828125e-4f;
        }
    }
    __syncthreads();

    // ---- noisy + top-8 + softmaxes: wave w -> rows w*4..+3, lane = expert ----
    const float bwv = bw[lane];
    const float bnv = bn[lane];
    for (int q = 0; q < 4; ++q) {
        const int lrow = w * 4 + q;
        const int grow = row0 + lrow;
        const float lwv = lw_s[lrow * 65 + lane] + bwv;
        const float lnv = ln_s[lrow * 65 + lane] + bnv;
        const float nz  = noise[(size_t)grow * 64 + lane];
        const float v   = lwv + nz * softplus_f(lnv);

        float cur2 = v;
        float m8 = 0.0f;
        int winIdx = 0;
        bool picked = false;
#pragma unroll
        for (int r = 0; r < 8; ++r) {
            float bvv = cur2;
            int   bi  = lane;
#pragma unroll
            for (int off = 32; off; off >>= 1) {
                const float ov = __shfl_xor(bvv, off);
                const int   oi = __shfl_xor(bi, off);
                if (ov > bvv || (ov == bvv && oi < bi)) { bvv = ov; bi = oi; }
            }
            if (r == 0) m8 = bvv;
            if (lane == r) winIdx = bi;
            if (lane == bi) { picked = true; cur2 = -INFINITY; }
        }

        const float pf = expf(v - m8);
        const float pg = picked ? pf : 0.0f;
        float sf = pf, sg = pg;
#pragma unroll
        for (int off = 32; off; off >>= 1) {
            sf += __shfl_xor(sf, off);
            sg += __shfl_xor(sg, off);
        }

        out_full [(size_t)grow * 64 + lane] = pf / sf;
        out_gates[(size_t)grow * 64 + lane] = pg / sg;
        if (lane < 8) out_ix[(size_t)grow * 8 + lane] = (float)winIdx;
    }
}

extern "C" void kernel_launch(void* const* d_in, const int* in_sizes, int n_in,
                              void* d_out, int out_size, void* d_ws, size_t ws_size,
                              hipStream_t stream) {
    const float* h  = (const float*)d_in[0];
    const float* Ww = (const float*)d_in[1];
    const float* bw = (const float*)d_in[2];
    const float* Wn = (const float*)d_in[3];
    const float* bn = (const float*)d_in[4];
    const float* nz = (const float*)d_in[5];

    const int rows = in_sizes[5] / 64;   // 32768

    float* out = (float*)d_out;
    float* og = out;
    float* oi = out + (size_t)rows * 64;
    float* of = out + (size_t)rows * 64 + (size_t)rows * 8;

    char* Wp = (char*)d_ws;   // 128 k-tiles * 16384 B = 2 MB

    hipLaunchKernelGGL(wconv_kernel, dim3(256), dim3(256), 0, stream, Ww, Wn, Wp);
    hipLaunchKernelGGL(router_kernel, dim3(rows / 16), dim3(256), 0, stream,
                       h, bw, bn, nz, Wp, og, oi, of);
}

// Round 19
// 267.536 us; speedup vs baseline: 1.3421x; 1.3421x over previous
//
#include <hip/hip_runtime.h>
#include <hip/hip_bf16.h>
#include <math.h>

// NoisyTopkRouter: rows=32768, D=4096, E=64, k=8.
// R19: R8 skeleton (triple-buffer, counted vmcnt, 2 barriers/step) at BM=128.
// 256 blocks (1/CU), 512 thr (8 waves, 2x4: wave = 64 rows x 32 vcols).
// h: reg-staged, fp16x2 split ONCE at staging -> LDS planes; W: 16KB/tile
// image DMA'd (2 gl16/wave). 24 MFMA/wave/step. fold-16-tiles.
// Output (fp32): gates[rows*64] | ix[rows*8] | full[rows*64]

typedef __attribute__((ext_vector_type(8))) _Float16 f16x8;
typedef __attribute__((ext_vector_type(4))) float f32x4;
typedef unsigned int u32;

#define D_DIM 4096
#define NSTEP 128
#define WTILE 16384          // per-k-tile W image: 2 planes x 8KB
// buffer: h-lo 8KB | h-hi 8KB | W 16KB = 32KB; 3 buffers
#define BUF_BYTES 32768
#define SMEM_BYTES 98304

__device__ __forceinline__ float softplus_f(float x) {
    return fmaxf(x, 0.0f) + log1pf(expf(-fabsf(x)));
}

__device__ __forceinline__ void gl16(void* lds, const void* g) {
    __builtin_amdgcn_global_load_lds(
        (const __attribute__((address_space(1))) u32*)g,
        (__attribute__((address_space(3))) u32*)lds, 16, 0, 0);
}

#define MFMA16F(A, B, C) __builtin_amdgcn_mfma_f32_16x16x32_f16((A), (B), (C), 0, 0, 0)

// ---- W pre-conversion (unchanged): 2 fp16 planes (p0=f16(w), p1=f16((w-p0)*2048)),
// per-k-tile 16KB image, chunk-swizzled sc = c4 ^ ((vrow>>2)&3)
__global__ __launch_bounds__(256)
void wconv_kernel(const float* __restrict__ Ww, const float* __restrict__ Wn,
                  char* __restrict__ Wp)
{
    const int bid = blockIdx.x;
    const int kc = bid >> 1, half = bid & 1;
    const int t = threadIdx.x;
    const int vrow = half * 64 + (t >> 2);
    const int c4 = t & 3;
    const float* src = (vrow < 64) ? (Ww + (size_t)vrow * D_DIM)
                                   : (Wn + (size_t)(vrow - 64) * D_DIM);
    const float4 a = *reinterpret_cast<const float4*>(src + kc * 32 + c4 * 8);
    const float4 b = *reinterpret_cast<const float4*>(src + kc * 32 + c4 * 8 + 4);
    const float f[8] = {a.x, a.y, a.z, a.w, b.x, b.y, b.z, b.w};
    union { _Float16 h[8]; uint4 q; } P0, P1;
#pragma unroll
    for (int i = 0; i < 8; ++i) {
        _Float16 lo = (_Float16)f[i];
        P0.h[i] = lo;
        P1.h[i] = (_Float16)((f[i] - (float)lo) * 2048.0f);
    }
    const int sc = c4 ^ ((vrow >> 2) & 3);
    char* dst = Wp + (size_t)kc * WTILE + vrow * 64 + sc * 16;
    *reinterpret_cast<uint4*>(dst)        = P0.q;
    *reinterpret_cast<uint4*>(dst + 8192) = P1.q;
}

__global__ __launch_bounds__(512, 2)
void router_kernel(const float* __restrict__ h,
                   const float* __restrict__ bw,
                   const float* __restrict__ bn,
                   const float* __restrict__ noise,
                   const char* __restrict__ Wp,
                   float* __restrict__ out_gates,
                   float* __restrict__ out_ix,
                   float* __restrict__ out_full)
{
    __shared__ __align__(16) char smem[SMEM_BYTES];

    const int t = threadIdx.x;
    const int lane = t & 63, w = t >> 6;    // 8 waves
    const int c = lane & 15, kg = lane >> 4;
    const int wr = w >> 2, wc = w & 3;      // wave = rows wr*64.., vcols wc*32..
    const int row0 = blockIdx.x * 128;      // 256 blocks = 1/CU

    // ---- h staging: thread -> row t>>2 (0..127), 8 fp32 at (t&3)*8 ----
    const int hrow = t >> 2, hc = t & 3;
    const float* hp = h + (size_t)(row0 + hrow) * D_DIM + hc * 8;
    const int hs = ((hrow >> 2) & 3) ^ hc;                 // write swizzle
    const int hwb = hrow * 64 + hs * 16;
    // ---- W staging: 2 gl16/wave, linear copy of 16KB tile image ----
    const char* wsrc = Wp + w * 2048 + lane * 16;

    // A-frag read offsets (per fi): arow = wr*64+fi*16+c, chunk kg
    int aoff[4];
#pragma unroll
    for (int fi = 0; fi < 4; ++fi) {
        const int arow = wr * 64 + fi * 16 + c;
        aoff[fi] = arow * 64 + ((((arow >> 2) & 3) ^ kg) * 16);
    }
    // B-frag offsets (per j): brow = wc*32+j*16+c
    int boff[2];
#pragma unroll
    for (int j = 0; j < 2; ++j) {
        const int brow = wc * 32 + j * 16 + c;
        boff[j] = 16384 + brow * 64 + ((kg ^ ((brow >> 2) & 3)) * 16);
    }

    f32x4 grp[4][2], sAc[4][2], aM[4][2];
#pragma unroll
    for (int fi = 0; fi < 4; ++fi)
#pragma unroll
        for (int j = 0; j < 2; ++j) {
            grp[fi][j] = (f32x4)0.0f; sAc[fi][j] = (f32x4)0.0f;
            aM[fi][j] = (f32x4)0.0f;
        }

    float4 hvA0, hvA1, hvB0, hvB1;   // 2 named prefetch sets (rule #20)

#define HCONV(BUF, V0, V1) {                                                  \
        union { _Float16 q[8]; uint4 u; } Lo_, Hi_;                           \
        const float ff[8] = {(V0).x, (V0).y, (V0).z, (V0).w,                  \
                             (V1).x, (V1).y, (V1).z, (V1).w};                 \
        _Pragma("unroll")                                                     \
        for (int i = 0; i < 8; ++i) {                                         \
            _Float16 lo_ = (_Float16)ff[i];                                   \
            Lo_.q[i] = lo_;                                                   \
            Hi_.q[i] = (_Float16)((ff[i] - (float)lo_) * 2048.0f);            \
        }                                                                     \
        *reinterpret_cast<uint4*>((BUF) + hwb) = Lo_.u;                       \
        *reinterpret_cast<uint4*>((BUF) + 8192 + hwb) = Hi_.u;                \
    }

    // ---- prologue: [W0,h0] [W1,h1] -> vmcnt(4) -> convert h0 -> barrier ----
    gl16(smem + 16384 + w * 2048,        wsrc);
    gl16(smem + 16384 + w * 2048 + 1024, wsrc + 1024);
    __builtin_amdgcn_sched_barrier(0);
    hvA0 = *reinterpret_cast<const float4*>(hp);
    hvA1 = *reinterpret_cast<const float4*>(hp + 4);
    __builtin_amdgcn_sched_barrier(0);
    gl16(smem + BUF_BYTES + 16384 + w * 2048,        wsrc + WTILE);
    gl16(smem + BUF_BYTES + 16384 + w * 2048 + 1024, wsrc + WTILE + 1024);
    __builtin_amdgcn_sched_barrier(0);
    hvB0 = *reinterpret_cast<const float4*>(hp + 32);
    hvB1 = *reinterpret_cast<const float4*>(hp + 36);
    asm volatile("s_waitcnt vmcnt(4)" ::: "memory");   // W0 + h0 retired
    __builtin_amdgcn_sched_barrier(0);
    HCONV(smem, hvA0, hvA1)
    asm volatile("s_waitcnt lgkmcnt(0)" ::: "memory");
    __builtin_amdgcn_sched_barrier(0);
    __builtin_amdgcn_s_barrier();
    __builtin_amdgcn_sched_barrier(0);

    // ---- main loop ----
    for (int kc = 0; kc < NSTEP; ++kc) {
        const char* bufc = smem + (kc % 3) * BUF_BYTES;

        // issue step kc+2 (W -> buf[(kc+2)%3], h -> reg set kc&1)
        if (kc + 2 < NSTEP) {
            char* nb = smem + ((kc + 2) % 3) * BUF_BYTES;
            const char* ws = wsrc + (size_t)(kc + 2) * WTILE;
            gl16(nb + 16384 + w * 2048,        ws);
            gl16(nb + 16384 + w * 2048 + 1024, ws + 1024);
            __builtin_amdgcn_sched_barrier(0);
            if ((kc & 1) == 0) {
                hvA0 = *reinterpret_cast<const float4*>(hp + (size_t)(kc + 2) * 32);
                hvA1 = *reinterpret_cast<const float4*>(hp + (size_t)(kc + 2) * 32 + 4);
            } else {
                hvB0 = *reinterpret_cast<const float4*>(hp + (size_t)(kc + 2) * 32);
                hvB1 = *reinterpret_cast<const float4*>(hp + (size_t)(kc + 2) * 32 + 4);
            }
            __builtin_amdgcn_sched_barrier(0);
        }

        // ---- fragment reads ----
        f16x8 A0[4], A1[4];
#pragma unroll
        for (int fi = 0; fi < 4; ++fi) {
            A0[fi] = *reinterpret_cast<const f16x8*>(bufc + aoff[fi]);
            A1[fi] = *reinterpret_cast<const f16x8*>(bufc + 8192 + aoff[fi]);
        }
        const f16x8 B0lo = *reinterpret_cast<const f16x8*>(bufc + boff[0]);
        const f16x8 B0hi = *reinterpret_cast<const f16x8*>(bufc + boff[0] + 8192);
        const f16x8 B1lo = *reinterpret_cast<const f16x8*>(bufc + boff[1]);
        const f16x8 B1hi = *reinterpret_cast<const f16x8*>(bufc + boff[1] + 8192);
        asm volatile("s_waitcnt lgkmcnt(0)" ::: "memory");
        __builtin_amdgcn_sched_barrier(0);

        // ---- 24 MFMA ----
        __builtin_amdgcn_s_setprio(1);
#pragma unroll
        for (int fi = 0; fi < 4; ++fi) {
            grp[fi][0] = MFMA16F(A0[fi], B0lo, grp[fi][0]);
            aM [fi][0] = MFMA16F(A0[fi], B0hi, aM [fi][0]);
            aM [fi][0] = MFMA16F(A1[fi], B0lo, aM [fi][0]);
            grp[fi][1] = MFMA16F(A0[fi], B1lo, grp[fi][1]);
            aM [fi][1] = MFMA16F(A0[fi], B1hi, aM [fi][1]);
            aM [fi][1] = MFMA16F(A1[fi], B1lo, aM [fi][1]);
        }
        __builtin_amdgcn_s_setprio(0);

        if ((kc & 15) == 15) {   // fold every 16 k-tiles (same as R8)
#pragma unroll
            for (int fi = 0; fi < 4; ++fi)
#pragma unroll
                for (int j = 0; j < 2; ++j) {
#pragma unroll
                    for (int e = 0; e < 4; ++e) sAc[fi][j][e] += grp[fi][j][e];
                    grp[fi][j] = (f32x4)0.0f;
                }
        }

        // retire step kc+1's loads (W stays pipelined), convert its h
        if (kc + 2 < NSTEP) asm volatile("s_waitcnt vmcnt(4)" ::: "memory");
        else                asm volatile("s_waitcnt vmcnt(0)" ::: "memory");
        __builtin_amdgcn_sched_barrier(0);
        if (kc + 1 < NSTEP) {
            char* cb = smem + ((kc + 1) % 3) * BUF_BYTES;
            if ((kc & 1) == 0) { HCONV(cb, hvB0, hvB1) }
            else               { HCONV(cb, hvA0, hvA1) }
        }
        asm volatile("s_waitcnt lgkmcnt(0)" ::: "memory");
        __builtin_amdgcn_sched_barrier(0);
        __builtin_amdgcn_s_barrier();
        __builtin_amdgcn_sched_barrier(0);
    }

    // ---- logits -> LDS overlay ----
    __syncthreads();
    float* lw_s = reinterpret_cast<float*>(smem);     // [128][65]
    float* ln_s = lw_s + 128 * 65;                    // [128][65]
    {
        float* dst = (wc < 2) ? lw_s : ln_s;
        const int eb = (wc & 1) * 32;
#pragma unroll
        for (int fi = 0; fi < 4; ++fi)
#pragma unroll
            for (int j = 0; j < 2; ++j)
#pragma unroll
                for (int e = 0; e < 4; ++e) {
                    const int rowl = wr * 64 + fi * 16 + kg * 4 + e;
                    dst[rowl * 65 + eb + j * 16 + c] =
                        sAc[fi][j][e] + aM[fi][j][e] * 4.8828125e-4f; // 2^-11
                }
    }
    __syncthreads();

    // ---- noisy + top-8 + softmaxes: wave w -> rows w*16..+15, lane = expert ----
    const float bwv = bw[lane];
    const float bnv = bn[lane];
    for (int q = 0; q < 16; ++q) {
        const int lrow = w * 16 + q;
        const int grow = row0 + lrow;
        const float lwv = lw_s[lrow * 65 + lane] + bwv;
        const float lnv = ln_s[lrow * 65 + lane] + bnv;
        const float nz  = noise[(size_t)grow * 64 + lane];
        const float v   = lwv + nz * softplus_f(lnv);

        float cur2 = v;
        float m8 = 0.0f;
        int winIdx = 0;
        bool picked = false;
#pragma unroll
        for (int r = 0; r < 8; ++r) {
            float bvv = cur2;
            int   bi  = lane;
#pragma unroll
            for (int off = 32; off; off >>= 1) {
                const float ov = __shfl_xor(bvv, off);
                const int   oi = __shfl_xor(bi, off);
                if (ov > bvv || (ov == bvv && oi < bi)) { bvv = ov; bi = oi; }
            }
            if (r == 0) m8 = bvv;
            if (lane == r) winIdx = bi;
            if (lane == bi) { picked = true; cur2 = -INFINITY; }
        }

        const float pf = expf(v - m8);
        const float pg = picked ? pf : 0.0f;
        float sf = pf, sg = pg;
#pragma unroll
        for (int off = 32; off; off >>= 1) {
            sf += __shfl_xor(sf, off);
            sg += __shfl_xor(sg, off);
        }

        out_full [(size_t)grow * 64 + lane] = pf / sf;
        out_gates[(size_t)grow * 64 + lane] = pg / sg;
        if (lane < 8) out_ix[(size_t)grow * 8 + lane] = (float)winIdx;
    }
}

extern "C" void kernel_launch(void* const* d_in, const int* in_sizes, int n_in,
                              void* d_out, int out_size, void* d_ws, size_t ws_size,
                              hipStream_t stream) {
    const float* h  = (const float*)d_in[0];
    const float* Ww = (const float*)d_in[1];
    const float* bw = (const float*)d_in[2];
    const float* Wn = (const float*)d_in[3];
    const float* bn = (const float*)d_in[4];
    const float* nz = (const float*)d_in[5];

    const int rows = in_sizes[5] / 64;   // 32768

    float* out = (float*)d_out;
    float* og = out;
    float* oi = out + (size_t)rows * 64;
    float* of = out + (size_t)rows * 64 + (size_t)rows * 8;

    char* Wp = (char*)d_ws;   // 128 k-tiles * 16384 B = 2 MB

    hipLaunchKernelGGL(wconv_kernel, dim3(256), dim3(256), 0, stream, Ww, Wn, Wp);
    hipLaunchKernelGGL(router_kernel, dim3(rows / 128), dim3(512), 0, stream,
                       h, bw, bn, nz, Wp, og, oi, of);
}

// Round 20
// 242.487 us; speedup vs baseline: 1.4807x; 1.1033x over previous
//
#include <hip/hip_runtime.h>
#include <hip/hip_bf16.h>
#include <math.h>

// NoisyTopkRouter: rows=32768, D=4096, E=64, k=8.
// FINAL (R8 restore, best measured 242.9 us): triple-buffered DMA pipeline,
// counted vmcnt + raw s_barrier, fp16x2 split (main + mid@2^11, 12 MFMA/step),
// 512-thread blocks (8 waves, 2x4 grid), W 2-plane fragment-ready image in d_ws.
// Output (fp32): gates[rows*64] | ix[rows*8] | full[rows*64]

typedef __attribute__((ext_vector_type(8))) _Float16 f16x8;
typedef __attribute__((ext_vector_type(4))) float f32x4;
typedef unsigned int u32;

#define BM 64
#define D_DIM 4096
#define NSTEP 128
#define WSTEP_BYTES 16384      // per-step W image: 2 planes x 8KB

// LDS: 3 buffers x (h 8KB + W 16KB) = 72KB
#define BUF_BYTES 24576
#define SMEM_BYTES 73728

__device__ __forceinline__ float softplus_f(float x) {
    return fmaxf(x, 0.0f) + log1pf(expf(-fabsf(x)));
}

__device__ __forceinline__ void gl16(void* lds, const void* g) {
    __builtin_amdgcn_global_load_lds(
        (const __attribute__((address_space(1))) u32*)g,
        (__attribute__((address_space(3))) u32*)lds, 16, 0, 0);
}

#define MFMA16F(A, B, C) __builtin_amdgcn_mfma_f32_16x16x32_f16((A), (B), (C), 0, 0, 0)

// ---- W pre-conversion: 2 fp16 planes (p0 = f16(w), p1 = f16((w-p0)*2048)),
// per-step 16KB fragment-ready image, chunk-swizzled: sc = c4 ^ ((vrow>>2)&3)
__global__ __launch_bounds__(256)
void wconv_kernel(const float* __restrict__ Ww, const float* __restrict__ Wn,
                  char* __restrict__ Wp)
{
    const int bid = blockIdx.x;            // 256 blocks
    const int kc = bid >> 1, half = bid & 1;
    const int t = threadIdx.x;
    const int vrow = half * 64 + (t >> 2); // 0..127 (0-63=Ww, 64-127=Wn)
    const int c4 = t & 3;                  // 16B chunk (8 fp32 k-elements -> 8 fp16)
    const float* src = (vrow < 64) ? (Ww + (size_t)vrow * D_DIM)
                                   : (Wn + (size_t)(vrow - 64) * D_DIM);
    const float4 a = *reinterpret_cast<const float4*>(src + kc * 32 + c4 * 8);
    const float4 b = *reinterpret_cast<const float4*>(src + kc * 32 + c4 * 8 + 4);
    const float f[8] = {a.x, a.y, a.z, a.w, b.x, b.y, b.z, b.w};
    union { _Float16 h[8]; uint4 q; } P0, P1;
#pragma unroll
    for (int i = 0; i < 8; ++i) {
        _Float16 lo = (_Float16)f[i];
        P0.h[i] = lo;
        P1.h[i] = (_Float16)((f[i] - (float)lo) * 2048.0f);
    }
    const int sc = c4 ^ ((vrow >> 2) & 3);
    char* dst = Wp + (size_t)kc * WSTEP_BYTES + vrow * 64 + sc * 16;
    *reinterpret_cast<uint4*>(dst)        = P0.q;
    *reinterpret_cast<uint4*>(dst + 8192) = P1.q;
}

__global__ __launch_bounds__(512, 4)
void router_kernel(const float* __restrict__ h,
                   const float* __restrict__ bw,
                   const float* __restrict__ bn,
                   const float* __restrict__ noise,
                   const char* __restrict__ Wp,
                   float* __restrict__ out_gates,
                   float* __restrict__ out_ix,
                   float* __restrict__ out_full)
{
    __shared__ __align__(16) char smem[SMEM_BYTES];

    const int t    = threadIdx.x;
    const int row0 = blockIdx.x * BM;
    const int lane = t & 63, w = t >> 6;        // 8 waves
    const int c = lane & 15, kg = lane >> 4;
    const int wr = w >> 2, wc = w & 3;          // 2x4 grid: rows wr*32.., vcols wc*32..

    // ---- staging geometry ----
    // h image[row*128 + sc*16] (raw fp32, sc = chunk ^ (row&7)): 1 gl16/thread
    const int hl  = lane >> 3;                  // row-within-8
    const int hsc = (lane & 7) ^ hl;            // pre-swizzled source chunk
    const float* hsrc = h + (size_t)(row0 + w * 8 + hl) * D_DIM + hsc * 4;
    const int hdst = w * 1024;                  // wave-uniform LDS base (+ lane*16 by DMA)
    const char* wsrc = Wp + w * 1024 + lane * 16;

    // ---- accumulators: grp (fold-16 main), sA, accM (@2^11) ----
    f32x4 grp[2][2], sA[2][2], accM[2][2];
#pragma unroll
    for (int fi = 0; fi < 2; ++fi)
#pragma unroll
        for (int j = 0; j < 2; ++j) {
            grp[fi][j] = (f32x4)0.0f; sA[fi][j] = (f32x4)0.0f;
            accM[fi][j] = (f32x4)0.0f;
        }

    // ---- prologue: stage steps 0 and 1 into bufs 0,1 ----
#pragma unroll
    for (int p = 0; p < 2; ++p) {
        char* nb = smem + p * BUF_BYTES;
        gl16(nb + hdst, hsrc + (size_t)p * 32);
        const char* ws = wsrc + (size_t)p * WSTEP_BYTES;
        gl16(nb + 8192 + w * 1024, ws);
        gl16(nb + 16384 + w * 1024, ws + 8192);
    }
    asm volatile("s_waitcnt vmcnt(3)" ::: "memory");   // step-0 loads done
    __builtin_amdgcn_sched_barrier(0);
    __builtin_amdgcn_s_barrier();
    __builtin_amdgcn_sched_barrier(0);

    for (int kc = 0; kc < NSTEP; ++kc) {
        // issue step kc+2 into buf (kc+2)%3 (stays in flight across this step)
        if (kc + 2 < NSTEP) {
            char* nb = smem + ((kc + 2) % 3) * BUF_BYTES;
            gl16(nb + hdst, hsrc + (size_t)(kc + 2) * 32);
            const char* ws = wsrc + (size_t)(kc + 2) * WSTEP_BYTES;
            gl16(nb + 8192 + w * 1024, ws);
            gl16(nb + 16384 + w * 1024, ws + 8192);
        }

        const char* hb = smem + (kc % 3) * BUF_BYTES;
        const char* wb = hb + 8192;

        // ---- A fragments: read raw fp32 h, fp16x2 split in-register ----
        f16x8 A0[2], A1[2];
#pragma unroll
        for (int fi = 0; fi < 2; ++fi) {
            const int arow = wr * 32 + fi * 16 + c;
            const int s0 = ((kg * 2)     ^ (arow & 7)) * 16;
            const int s1 = ((kg * 2 + 1) ^ (arow & 7)) * 16;
            const float4 fa = *reinterpret_cast<const float4*>(hb + arow * 128 + s0);
            const float4 fb = *reinterpret_cast<const float4*>(hb + arow * 128 + s1);
            const float f[8] = {fa.x, fa.y, fa.z, fa.w, fb.x, fb.y, fb.z, fb.w};
#pragma unroll
            for (int i = 0; i < 8; ++i) {
                _Float16 lo = (_Float16)f[i];
                A0[fi][i] = lo;
                A1[fi][i] = (_Float16)((f[i] - (float)lo) * 2048.0f);
            }
        }

        // ---- B fragments + 3-term MFMA ----
#pragma unroll
        for (int j = 0; j < 2; ++j) {
            const int brow = wc * 32 + j * 16 + c;
            const int bo = brow * 64 + ((kg ^ ((brow >> 2) & 3)) * 16);
            const f16x8 B0 = *reinterpret_cast<const f16x8*>(wb + bo);
            const f16x8 B1 = *reinterpret_cast<const f16x8*>(wb + bo + 8192);
#pragma unroll
            for (int fi = 0; fi < 2; ++fi) {
                grp[fi][j]  = MFMA16F(A0[fi], B0, grp[fi][j]);
                accM[fi][j] = MFMA16F(A0[fi], B1, accM[fi][j]);
                accM[fi][j] = MFMA16F(A1[fi], B0, accM[fi][j]);
            }
        }

        // fold group into sA every 16 steps (last fold at kc=127)
        if ((kc & 15) == 15) {
#pragma unroll
            for (int fi = 0; fi < 2; ++fi)
#pragma unroll
                for (int j = 0; j < 2; ++j) {
#pragma unroll
                    for (int e = 0; e < 4; ++e) sA[fi][j][e] += grp[fi][j][e];
                    grp[fi][j] = (f32x4)0.0f;
                }
        }

        // counted wait: step kc+1's loads complete, kc+2's stay in flight
        if (kc + 2 < NSTEP) {
            asm volatile("s_waitcnt vmcnt(3)" ::: "memory");
        } else {
            asm volatile("s_waitcnt vmcnt(0)" ::: "memory");
        }
        __builtin_amdgcn_sched_barrier(0);
        __builtin_amdgcn_s_barrier();
        __builtin_amdgcn_sched_barrier(0);
    }

    // ---- logits -> LDS ----
    // C/D layout: col = lane&15, row = (lane>>4)*4 + reg
    float* lw_s = reinterpret_cast<float*>(smem);            // [64][65]
    float* ln_s = lw_s + 64 * 65;                            // [64][65]
    float* dst = (wc < 2) ? lw_s : ln_s;
#pragma unroll
    for (int fi = 0; fi < 2; ++fi)
#pragma unroll
        for (int j = 0; j < 2; ++j)
#pragma unroll
            for (int r = 0; r < 4; ++r) {
                const int rowl = wr * 32 + fi * 16 + kg * 4 + r;
                const int e = (wc & 1) * 32 + j * 16 + c;
                dst[rowl * 65 + e] = sA[fi][j][r] + accM[fi][j][r] * 4.8828125e-4f; // 2^-11
            }
    __syncthreads();

    // ---- noisy + top-8 + softmaxes: wave w -> rows w*8..w*8+7, lane = expert ----
    const float bwv = bw[lane];
    const float bnv = bn[lane];
    for (int q = 0; q < 8; ++q) {
        const int lrow = w * 8 + q;
        const int grow = row0 + lrow;
        const float lwv = lw_s[lrow * 65 + lane] + bwv;
        const float lnv = ln_s[lrow * 65 + lane] + bnv;
        const float nz  = noise[(size_t)grow * 64 + lane];
        const float v   = lwv + nz * softplus_f(lnv);

        float cur2 = v;
        float m8 = 0.0f;
        int winIdx = 0;
        bool picked = false;
#pragma unroll
        for (int r = 0; r < 8; ++r) {
            float bvv = cur2;
            int   bi  = lane;
#pragma unroll
            for (int off = 32; off; off >>= 1) {
                const float ov = __shfl_xor(bvv, off);
                const int   oi = __shfl_xor(bi, off);
                if (ov > bvv || (ov == bvv && oi < bi)) { bvv = ov; bi = oi; }
            }
            if (r == 0) m8 = bvv;
            if (lane == r) winIdx = bi;
            if (lane == bi) { picked = true; cur2 = -INFINITY; }
        }

        const float pf = expf(v - m8);
        const float pg = picked ? pf : 0.0f;
        float sf = pf, sg = pg;
#pragma unroll
        for (int off = 32; off; off >>= 1) {
            sf += __shfl_xor(sf, off);
            sg += __shfl_xor(sg, off);
        }

        out_full [(size_t)grow * 64 + lane] = pf / sf;
        out_gates[(size_t)grow * 64 + lane] = pg / sg;
        if (lane < 8) out_ix[(size_t)grow * 8 + lane] = (float)winIdx;
    }
}

extern "C" void kernel_launch(void* const* d_in, const int* in_sizes, int n_in,
                              void* d_out, int out_size, void* d_ws, size_t ws_size,
                              hipStream_t stream) {
    const float* h  = (const float*)d_in[0];
    const float* Ww = (const float*)d_in[1];
    const float* bw = (const float*)d_in[2];
    const float* Wn = (const float*)d_in[3];
    const float* bn = (const float*)d_in[4];
    const float* nz = (const float*)d_in[5];

    const int rows = in_sizes[5] / 64;   // 32768

    float* out = (float*)d_out;
    float* og = out;
    float* oi = out + (size_t)rows * 64;
    float* of = out + (size_t)rows * 64 + (size_t)rows * 8;

    char* Wp = (char*)d_ws;   // 128 steps * 16384 B = 2 MB

    hipLaunchKernelGGL(wconv_kernel, dim3(256), dim3(256), 0, stream, Ww, Wn, Wp);
    hipLaunchKernelGGL(router_kernel, dim3(rows / BM), dim3(512), 0, stream,
                       h, bw, bn, nz, Wp, og, oi, of);
}